// Round 5
// baseline (419.671 us; speedup 1.0000x reference)
//
#include <hip/hip_runtime.h>

#define NN 10000
#define NEDGE 160000
#define NBATCH 64

// ---------------- workspace layout (units: floats) ----------------
static constexpr size_t OFF_POS   = 0;                     // N*3
static constexpr size_t OFF_H     = 30016;                 // N*64
static constexpr size_t OFF_NF0   = OFF_H   + 640000;      // N*64
static constexpr size_t OFF_NUP   = OFF_NF0 + 640000;      // N*64
static constexpr size_t OFF_V3    = OFF_NUP + 640000;      // N*192
static constexpr size_t OFF_Q1    = OFF_V3  + 1920000;     // (unused)
static constexpr size_t OFF_AGG   = OFF_Q1  + 640000;      // N*256 (float4[N*64])
static constexpr size_t OFF_WW    = OFF_AGG + 2560000;     // E*64
static constexpr size_t OFF_WY    = OFF_WW  + 10240000;    // E*4 (float4[E])
static constexpr size_t OFF_ESLOT = OFF_WY  + 640000;      // E ints
static constexpr size_t OFF_CSR   = OFF_ESLOT + 160000;    // N+1 ints (pad 10016)
static constexpr size_t OFF_CNT   = OFF_CSR + 10016;       // N ints
static constexpr size_t OFF_CUR   = OFF_CNT + 10016;       // N ints
static constexpr size_t OFF_BACC  = OFF_CUR + 10016;       // B*4 floats
static constexpr size_t WS_END    = OFF_BACC + 256;

__device__ __forceinline__ float silu_f(float x) {
  return x / (1.0f + __expf(-x));
}

// ---------------- setup ----------------
// blocks [0,2500): h = [na/4, t[batch]]@W_emb + b_emb ; nf0 = h ; pos_cur = positions
//                  then fused: nfup0 = h @ Wup0 (row exchanged via LDS)
// blocks [2500,3125): histogram of rcv into counts
__global__ __launch_bounds__(256) void k_embed_count_up(
    const float* __restrict__ pos_in, const float* __restrict__ na,
    const float* __restrict__ t, const int* __restrict__ batch,
    const float* __restrict__ Wemb, const float* __restrict__ bemb,
    const float* __restrict__ Wup0,
    float* __restrict__ h, float* __restrict__ nf0, float* __restrict__ pos_cur,
    float* __restrict__ nfup0,
    const int* __restrict__ ei, int* __restrict__ counts) {
  if (blockIdx.x >= 2500) {
    int e = (blockIdx.x - 2500) * 256 + threadIdx.x;   // exactly E threads
    atomicAdd(&counts[ei[NEDGE + e]], 1);
    return;
  }
  __shared__ float sx[4][64];
  int tid = blockIdx.x * 256 + threadIdx.x;   // exactly N*64 threads
  int n = tid >> 6, k = tid & 63;
  int w = threadIdx.x >> 6;
  float acc = bemb[k];
  const float* arow = na + n * 10;
#pragma unroll
  for (int j = 0; j < 10; ++j)
    acc = fmaf(arow[j] * 0.25f, Wemb[j * 64 + k], acc);
  acc = fmaf(t[batch[n]], Wemb[10 * 64 + k], acc);
  h[tid] = acc;
  nf0[tid] = acc;
  if (k < 3) pos_cur[n * 3 + k] = pos_in[n * 3 + k];
  sx[w][k] = acc;
  __syncthreads();
  float up = 0.f;
  for (int hh = 0; hh < 64; ++hh)
    up = fmaf(sx[w][hh], Wup0[hh * 64 + k], up);
  nfup0[tid] = up;
}

// single-block exclusive scan: thread owns 10 elems, one 1024-wide scan of partials
__global__ __launch_bounds__(1024) void k_scan(const int* __restrict__ counts,
                                               int* __restrict__ offs) {
  __shared__ int part[1024];
  int tid = threadIdx.x;
  int base = tid * 10;
  int local[10];
  int s = 0;
#pragma unroll
  for (int j = 0; j < 10; ++j) {
    int idx = base + j;
    int v = (idx < NN) ? counts[idx] : 0;
    local[j] = s;
    s += v;
  }
  part[tid] = s;
  __syncthreads();
  for (int d = 1; d < 1024; d <<= 1) {
    int v = (tid >= d) ? part[tid - d] : 0;
    __syncthreads();
    part[tid] += v;
    __syncthreads();
  }
  int excl = (tid == 0) ? 0 : part[tid - 1];
#pragma unroll
  for (int j = 0; j < 10; ++j) {
    int idx = base + j;
    if (idx < NN) offs[idx] = excl + local[j];
  }
  if (tid == 1023) offs[NN] = excl + s;
}

// eslot[e] = CSR slot of edge e (grouped by rcv)
__global__ __launch_bounds__(256) void k_scatter(
    const int* __restrict__ ei, const int* __restrict__ offs,
    int* __restrict__ cursor, int* __restrict__ eslot) {
  int e = blockIdx.x * 256 + threadIdx.x;
  int r = ei[NEDGE + e];
  int slot = atomicAdd(&cursor[r], 1);
  eslot[e] = offs[r] + slot;
}

// ---------------- per-layer ----------------
// k_edge v3: 4 edges/thread x 32 outputs/thread.
// Block = 256 threads covers 512 edges. Threads 0-127: outputs 0-31 (half 0),
// threads 128-255: outputs 32-63 (half 1). Weight delivery per wave drops
// 1024 -> 512 ds_read_b128, and wave count halves -> LDS pipe ~12.5us model.
__global__ __launch_bounds__(256) void k_edge(
    const int* __restrict__ ei, const float* __restrict__ shifts,
    const float* __restrict__ pos, const float* __restrict__ nfup0,
    const float* __restrict__ Wr1, const float* __restrict__ br1,
    const float* __restrict__ Wr2, const int* __restrict__ eslot,
    float* __restrict__ w_s, float4* __restrict__ y_s) {
  __shared__ float4 sW[1024];          // Wr2 as [64 rows][16 float4]
  __shared__ float sW1[64];
  __shared__ float sB1[64];
  {
    const float4* W4 = (const float4*)Wr2;
    for (int i = threadIdx.x; i < 1024; i += 256) sW[i] = W4[i];
    if (threadIdx.x < 64) { sW1[threadIdx.x] = Wr1[threadIdx.x]; sB1[threadIdx.x] = br1[threadIdx.x]; }
  }
  __syncthreads();
  int half = threadIdx.x >> 7;         // wave-uniform (waves 0-1: 0, waves 2-3: 1)
  int sub  = threadIdx.x & 127;
  int ebase = blockIdx.x * 512 + sub * 4;

  float len[4]; int slot[4]; int snd[4]; bool v[4];
#pragma unroll
  for (int q = 0; q < 4; ++q) {
    int e = ebase + q;
    v[q] = e < NEDGE;
    int ec = v[q] ? e : 0;
    int s = ei[ec], r = ei[NEDGE + ec];
    snd[q] = s;
    float vx = pos[r * 3 + 0] - pos[s * 3 + 0] + shifts[ec * 3 + 0];
    float vy = pos[r * 3 + 1] - pos[s * 3 + 1] + shifts[ec * 3 + 1];
    float vz = pos[r * 3 + 2] - pos[s * 3 + 2] + shifts[ec * 3 + 2];
    float l = sqrtf(vx * vx + vy * vy + vz * vz);
    len[q] = l;
    slot[q] = eslot[ec];
    if (half == 0 && v[q]) {
      float inv = 1.0f / (l + 1e-9f);
      const float c1 = 1.7320508f * 0.0625f;   // sqrt(3)/AVG_NEIGH
      y_s[slot[q]] = make_float4(0.0625f, c1 * vx * inv, c1 * vy * inv, c1 * vz * inv);
    }
  }

  float4 acc[4][8];
#pragma unroll
  for (int q = 0; q < 4; ++q)
#pragma unroll
    for (int j = 0; j < 8; ++j) acc[q][j] = make_float4(0.f, 0.f, 0.f, 0.f);

  const float4* sWh = sW + half * 8;   // this half's 8 float4 per row
  for (int hh = 0; hh < 64; ++hh) {
    float w1 = sW1[hh], b1 = sB1[hh];
    float sl[4];
#pragma unroll
    for (int q = 0; q < 4; ++q)
      sl[q] = silu_f(fmaf(len[q], w1, b1));
#pragma unroll
    for (int j = 0; j < 8; ++j) {
      float4 wq = sWh[hh * 16 + j];    // wave-uniform addr -> broadcast, no conflict
#pragma unroll
      for (int q = 0; q < 4; ++q) {
        acc[q][j].x = fmaf(sl[q], wq.x, acc[q][j].x);
        acc[q][j].y = fmaf(sl[q], wq.y, acc[q][j].y);
        acc[q][j].z = fmaf(sl[q], wq.z, acc[q][j].z);
        acc[q][j].w = fmaf(sl[q], wq.w, acc[q][j].w);
      }
    }
  }

  // epilogue: w = acc * nfup0[snd, half*32 .. half*32+32), write to CSR slot
#pragma unroll
  for (int q = 0; q < 4; ++q) {
    if (!v[q]) continue;
    const float4* nrow = (const float4*)(nfup0 + (size_t)snd[q] * 64) + half * 8;
    float4* wrow = (float4*)(w_s + (size_t)slot[q] * 64) + half * 8;
#pragma unroll
    for (int j = 0; j < 8; ++j) {
      float4 nv = nrow[j];
      float4 o;
      o.x = acc[q][j].x * nv.x; o.y = acc[q][j].y * nv.y;
      o.z = acc[q][j].z * nv.z; o.w = acc[q][j].w * nv.w;
      wrow[j] = o;
    }
  }
}

// wave-per-node CSR gather: agg[n,k,0:4] = sum_e w[e,k]*Y4[e,:]
__global__ __launch_bounds__(256) void k_gather(
    const int* __restrict__ offs, const float* __restrict__ w_s,
    const float4* __restrict__ y_s, float4* __restrict__ agg) {
  int gtid = blockIdx.x * 256 + threadIdx.x;  // N*64 threads, wave per node
  int n = gtid >> 6;
  int lane = threadIdx.x & 63;
  int beg = offs[n], end = offs[n + 1];
  float a0 = 0.f, a1 = 0.f, a2 = 0.f, a3 = 0.f;
  for (int j = beg; j < end; ++j) {
    float w = w_s[(size_t)j * 64 + lane];
    float4 y = y_s[j];
    a0 = fmaf(w, y.x, a0);
    a1 = fmaf(w, y.y, a1);
    a2 = fmaf(w, y.z, a2);
    a3 = fmaf(w, y.w, a3);
  }
  agg[(size_t)n * 64 + lane] = make_float4(a0, a1, a2, a3);
}

// a = agg@Wmix ; f=1+s+s^2 ; nf=(a*f)@Wprod ; nf0=nf[...,0], v3=nf[...,1:4]
// optionally: nfup0 = nf0_row @ Wup_next (fused next-layer up).  512 thr, 56KB LDS.
__global__ __launch_bounds__(512) void k_mix_prod(
    const float4* __restrict__ agg, const float* __restrict__ Wmix,
    const float* __restrict__ Wprod, float* __restrict__ nf0,
    float* __restrict__ v3, const float* __restrict__ Wup_next,
    float* __restrict__ nfup0) {
  __shared__ float sMix[4096];
  __shared__ float sProd[4096];
  __shared__ float sUp[4096];
  __shared__ float4 xb[8][64];
  for (int i = threadIdx.x; i < 4096; i += 512) { sMix[i] = Wmix[i]; sProd[i] = Wprod[i]; }
  if (Wup_next)
    for (int i = threadIdx.x; i < 4096; i += 512) sUp[i] = Wup_next[i];
  int w = threadIdx.x >> 6, lane = threadIdx.x & 63;
  __syncthreads();
  for (int it = 0; it < 5; ++it) {
    int n = it * 2000 + blockIdx.x * 8 + w;   // grid 250: covers 0..9999 exactly
    xb[w][lane] = agg[(size_t)n * 64 + lane];
    __syncthreads();
    float4 a = make_float4(0.f, 0.f, 0.f, 0.f);
    for (int hh = 0; hh < 64; ++hh) {
      float4 x = xb[w][hh];
      float m = sMix[hh * 64 + lane];
      a.x = fmaf(x.x, m, a.x); a.y = fmaf(x.y, m, a.y);
      a.z = fmaf(x.z, m, a.z); a.w = fmaf(x.w, m, a.w);
    }
    float sv = a.x;
    float f = 1.0f + sv + sv * sv;
    a.x *= f; a.y *= f; a.z *= f; a.w *= f;
    __syncthreads();
    xb[w][lane] = a;
    __syncthreads();
    float4 nf = make_float4(0.f, 0.f, 0.f, 0.f);
    for (int hh = 0; hh < 64; ++hh) {
      float4 x = xb[w][hh];
      float m = sProd[hh * 64 + lane];
      nf.x = fmaf(x.x, m, nf.x); nf.y = fmaf(x.y, m, nf.y);
      nf.z = fmaf(x.z, m, nf.z); nf.w = fmaf(x.w, m, nf.w);
    }
    nf0[(size_t)n * 64 + lane] = nf.x;
    v3[(size_t)n * 192 + lane * 3 + 0] = nf.y;
    v3[(size_t)n * 192 + lane * 3 + 1] = nf.z;
    v3[(size_t)n * 192 + lane * 3 + 2] = nf.w;
    if (Wup_next) {
      __syncthreads();
      xb[w][lane].x = nf.x;
      __syncthreads();
      float up = 0.f;
      for (int hh = 0; hh < 64; ++hh)
        up = fmaf(xb[w][hh].x, sUp[hh * 64 + lane], up);
      nfup0[(size_t)n * 64 + lane] = up;
    }
    __syncthreads();
  }
}

// fused readout + MLP: q=silu(sc@Wro1+b) ; gate=silu(sc@Wg) ; pos += sum v3*gate*wv ;
// scalars=q@Wro2 ; h += silu([h,scalars]@Wmlp1+b)@Wmlp2 + b2.   512 thr, ~107KB LDS.
__global__ __launch_bounds__(512) void k_readout_mlp(
    const float* __restrict__ nf0, const float* __restrict__ v3,
    const float* __restrict__ Wro1, const float* __restrict__ bro1,
    const float* __restrict__ Wg, const float* __restrict__ wvv,
    const float* __restrict__ Wro2,
    const float* __restrict__ Wmlp1, const float* __restrict__ bmlp1,
    const float* __restrict__ Wmlp2, const float* __restrict__ bmlp2,
    float* __restrict__ pos, float* __restrict__ h) {
  __shared__ float sR[4096];
  __shared__ float sG[4096];
  __shared__ float sRo2[4096];
  __shared__ float sM1[8192];
  __shared__ float sM2[4096];
  __shared__ float sx[8][64], sq[8][64], ssc[8][64], sh[8][64], su[8][64];
  __shared__ float swv[64];
  for (int i = threadIdx.x; i < 4096; i += 512) {
    sR[i] = Wro1[i]; sG[i] = Wg[i]; sRo2[i] = Wro2[i]; sM2[i] = Wmlp2[i];
  }
  for (int i = threadIdx.x; i < 8192; i += 512) sM1[i] = Wmlp1[i];
  if (threadIdx.x < 64) swv[threadIdx.x] = wvv[threadIdx.x];
  int w = threadIdx.x >> 6, lane = threadIdx.x & 63;
  __syncthreads();
  for (int it = 0; it < 5; ++it) {
    int n = it * 2000 + blockIdx.x * 8 + w;
    sx[w][lane] = nf0[(size_t)n * 64 + lane];
    sh[w][lane] = h[(size_t)n * 64 + lane];
    __syncthreads();
    float q = bro1[lane];
    float g = 0.f;
    for (int hh = 0; hh < 64; ++hh) {
      float x = sx[w][hh];
      q = fmaf(x, sR[hh * 64 + lane], q);
      g = fmaf(x, sG[hh * 64 + lane], g);
    }
    q = silu_f(q);
    g = silu_f(g);
    float gw = g * swv[lane];
    float p0 = v3[(size_t)n * 192 + lane * 3 + 0] * gw;
    float p1 = v3[(size_t)n * 192 + lane * 3 + 1] * gw;
    float p2 = v3[(size_t)n * 192 + lane * 3 + 2] * gw;
#pragma unroll
    for (int m = 32; m > 0; m >>= 1) {
      p0 += __shfl_xor(p0, m);
      p1 += __shfl_xor(p1, m);
      p2 += __shfl_xor(p2, m);
    }
    if (lane == 0) {
      pos[n * 3 + 0] += p0;
      pos[n * 3 + 1] += p1;
      pos[n * 3 + 2] += p2;
    }
    sq[w][lane] = q;
    __syncthreads();
    float sc = 0.f;
    for (int m = 0; m < 64; ++m) sc = fmaf(sq[w][m], sRo2[m * 64 + lane], sc);
    ssc[w][lane] = sc;
    __syncthreads();
    float u = bmlp1[lane];
    for (int j = 0; j < 64; ++j) u = fmaf(sh[w][j], sM1[j * 64 + lane], u);
    for (int j = 0; j < 64; ++j) u = fmaf(ssc[w][j], sM1[(64 + j) * 64 + lane], u);
    u = silu_f(u);
    su[w][lane] = u;
    __syncthreads();
    float ho = sh[w][lane] + bmlp2[lane];
    for (int m = 0; m < 64; ++m) ho = fmaf(su[w][m], sM2[m * 64 + lane], ho);
    h[(size_t)n * 64 + lane] = ho;
    __syncthreads();
  }
}

// ---------------- outputs ----------------
__global__ __launch_bounds__(256) void k_pred(
    const float* __restrict__ h, const float* __restrict__ Wout,
    const float* __restrict__ bout, float* __restrict__ out) {
  __shared__ float sW[704];
  for (int i = threadIdx.x; i < 704; i += 256) sW[i] = Wout[i];
  __syncthreads();
  int n = blockIdx.x * 256 + threadIdx.x;
  if (n >= NN) return;
  float acc[10];
#pragma unroll
  for (int j = 0; j < 10; ++j) acc[j] = bout[j];
  const float* row = h + (size_t)n * 64;
  for (int hh = 0; hh < 64; ++hh) {
    float hv = row[hh];
#pragma unroll
    for (int j = 0; j < 10; ++j) acc[j] = fmaf(hv, sW[hh * 11 + j], acc[j]);
  }
  float* orow = out + (size_t)n * 10;
#pragma unroll
  for (int j = 0; j < 10; ++j) orow[j] = acc[j];
}

// batch is SORTED: wave-level segmented reduce, atomics only at run heads
__global__ __launch_bounds__(256) void k_batch(
    const int* __restrict__ batch, const float* __restrict__ pos,
    float* __restrict__ bacc) {
  int n = blockIdx.x * 256 + threadIdx.x;
  int lane = threadIdx.x & 63;
  bool valid = n < NN;
  int b = valid ? batch[n] : -1;
  float p0 = valid ? pos[n * 3 + 0] : 0.f;
  float p1 = valid ? pos[n * 3 + 1] : 0.f;
  float p2 = valid ? pos[n * 3 + 2] : 0.f;
  float c  = valid ? 1.f : 0.f;
#pragma unroll
  for (int d = 1; d < 64; d <<= 1) {
    float q0 = __shfl_down(p0, d);
    float q1 = __shfl_down(p1, d);
    float q2 = __shfl_down(p2, d);
    float qc = __shfl_down(c, d);
    int bd   = __shfl_down(b, d);
    if (lane + d < 64 && bd == b) { p0 += q0; p1 += q1; p2 += q2; c += qc; }
  }
  int bprev = __shfl_up(b, 1);
  bool head = valid && (lane == 0 || bprev != b);
  if (head) {
    atomicAdd(&bacc[b * 4 + 0], p0);
    atomicAdd(&bacc[b * 4 + 1], p1);
    atomicAdd(&bacc[b * 4 + 2], p2);
    atomicAdd(&bacc[b * 4 + 3], c);
  }
}

__global__ __launch_bounds__(256) void k_predpos(
    const int* __restrict__ batch, const float* __restrict__ pos,
    const float* __restrict__ pos0, const float* __restrict__ bacc,
    float* __restrict__ out) {
  int n = blockIdx.x * 256 + threadIdx.x;
  if (n >= NN) return;
  int b = batch[n];
  float cnt = fmaxf(bacc[b * 4 + 3], 1.0f);
#pragma unroll
  for (int c = 0; c < 3; ++c)
    out[NN * 10 + n * 3 + c] = pos[n * 3 + c] - bacc[b * 4 + c] / cnt - pos0[n * 3 + c];
}

extern "C" void kernel_launch(void* const* d_in, const int* in_sizes, int n_in,
                              void* d_out, int out_size, void* d_ws, size_t ws_size,
                              hipStream_t stream) {
  const float* positions = (const float*)d_in[0];
  const float* node_attrs = (const float*)d_in[1];
  const float* t_in = (const float*)d_in[2];
  const float* shifts = (const float*)d_in[3];
  const int* batch = (const int*)d_in[4];
  const int* edge_index = (const int*)d_in[5];
  const float* W_emb = (const float*)d_in[6];
  const float* b_emb = (const float*)d_in[7];
  const float* W_out = (const float*)d_in[8];
  const float* b_out = (const float*)d_in[9];
  const float* Wr1 = (const float*)d_in[10];
  const float* br1 = (const float*)d_in[11];
  const float* Wr2 = (const float*)d_in[12];
  const float* W_up = (const float*)d_in[13];
  const float* W_mix = (const float*)d_in[14];
  const float* W_prod = (const float*)d_in[15];
  const float* Wro1 = (const float*)d_in[16];
  const float* bro1 = (const float*)d_in[17];
  const float* Wro2 = (const float*)d_in[18];
  const float* Wg = (const float*)d_in[19];
  const float* wv = (const float*)d_in[20];
  const float* Wmlp1 = (const float*)d_in[21];
  const float* bmlp1 = (const float*)d_in[22];
  const float* Wmlp2 = (const float*)d_in[23];
  const float* bmlp2 = (const float*)d_in[24];

  float* ws = (float*)d_ws;
  float* pos_cur = ws + OFF_POS;
  float* hbuf    = ws + OFF_H;
  float* nf0     = ws + OFF_NF0;
  float* nfup0   = ws + OFF_NUP;
  float* v3      = ws + OFF_V3;
  float4* agg    = (float4*)(ws + OFF_AGG);
  float* w_s     = ws + OFF_WW;
  float4* y_s    = (float4*)(ws + OFF_WY);
  int* eslot     = (int*)(ws + OFF_ESLOT);
  int* csroff    = (int*)(ws + OFF_CSR);
  int* counts    = (int*)(ws + OFF_CNT);
  int* cursor    = (int*)(ws + OFF_CUR);
  float* bacc    = ws + OFF_BACC;

  hipMemsetAsync(counts, 0, (WS_END - OFF_CNT) * sizeof(float), stream);

  k_embed_count_up<<<3125, 256, 0, stream>>>(positions, node_attrs, t_in, batch,
                                             W_emb, b_emb, W_up,
                                             hbuf, nf0, pos_cur, nfup0,
                                             edge_index, counts);
  k_scan<<<1, 1024, 0, stream>>>(counts, csroff);
  k_scatter<<<625, 256, 0, stream>>>(edge_index, csroff, cursor, eslot);

  for (int i = 0; i < 2; ++i) {
    k_edge<<<313, 256, 0, stream>>>(edge_index, shifts, pos_cur, nfup0,
                                    Wr1 + i * 64, br1 + i * 64, Wr2 + i * 4096,
                                    eslot, w_s, y_s);
    k_gather<<<2500, 256, 0, stream>>>(csroff, w_s, y_s, agg);
    k_mix_prod<<<250, 512, 0, stream>>>(agg, W_mix + i * 4096, W_prod + i * 4096,
                                        nf0, v3,
                                        (i == 0) ? (W_up + 4096) : nullptr, nfup0);
    k_readout_mlp<<<250, 512, 0, stream>>>(nf0, v3, Wro1 + i * 4096, bro1 + i * 64,
                                           Wg + i * 4096, wv + i * 64,
                                           Wro2 + i * 4096,
                                           Wmlp1 + i * 8192, bmlp1 + i * 64,
                                           Wmlp2 + i * 4096, bmlp2 + i * 64,
                                           pos_cur, hbuf);
  }

  k_pred<<<40, 256, 0, stream>>>(hbuf, W_out, b_out, (float*)d_out);
  k_batch<<<40, 256, 0, stream>>>(batch, pos_cur, bacc);
  k_predpos<<<40, 256, 0, stream>>>(batch, pos_cur, positions, bacc, (float*)d_out);
}

// Round 8
// 402.333 us; speedup vs baseline: 1.0431x; 1.0431x over previous
//
#include <hip/hip_runtime.h>

#define NN 10000
#define NEDGE 160000
#define NBATCH 64

// ---------------- workspace layout (units: floats) ----------------
static constexpr size_t OFF_POS   = 0;                     // N*3
static constexpr size_t OFF_H     = 30016;                 // N*64
static constexpr size_t OFF_NF0   = OFF_H   + 640000;      // N*64
static constexpr size_t OFF_NUP   = OFF_NF0 + 640000;      // N*64
static constexpr size_t OFF_V3    = OFF_NUP + 640000;      // N*192
static constexpr size_t OFF_Q1    = OFF_V3  + 1920000;     // (unused)
static constexpr size_t OFF_AGG   = OFF_Q1  + 640000;      // N*256 (float4[N*64])
static constexpr size_t OFF_WW    = OFF_AGG + 2560000;     // E*64
static constexpr size_t OFF_WY    = OFF_WW  + 10240000;    // E*4 (float4[E])
static constexpr size_t OFF_ESLOT = OFF_WY  + 640000;      // E ints
static constexpr size_t OFF_CSR   = OFF_ESLOT + 160000;    // N+1 ints (pad 10016)
static constexpr size_t OFF_CNT   = OFF_CSR + 10016;       // N ints
static constexpr size_t OFF_CUR   = OFF_CNT + 10016;       // N ints
static constexpr size_t OFF_BACC  = OFF_CUR + 10016;       // B*4 floats
static constexpr size_t WS_END    = OFF_BACC + 256;

__device__ __forceinline__ float silu_f(float x) {
  return x / (1.0f + __expf(-x));
}

// ---------------- setup ----------------
// blocks [0,2500): h = [na/4, t[batch]]@W_emb + b_emb ; nf0 = h ; pos_cur = positions
//                  then fused: nfup0 = h @ Wup0 (row exchanged via LDS)
// blocks [2500,3125): histogram of rcv into counts
__global__ __launch_bounds__(256) void k_embed_count_up(
    const float* __restrict__ pos_in, const float* __restrict__ na,
    const float* __restrict__ t, const int* __restrict__ batch,
    const float* __restrict__ Wemb, const float* __restrict__ bemb,
    const float* __restrict__ Wup0,
    float* __restrict__ h, float* __restrict__ nf0, float* __restrict__ pos_cur,
    float* __restrict__ nfup0,
    const int* __restrict__ ei, int* __restrict__ counts) {
  if (blockIdx.x >= 2500) {
    int e = (blockIdx.x - 2500) * 256 + threadIdx.x;   // exactly E threads
    atomicAdd(&counts[ei[NEDGE + e]], 1);
    return;
  }
  __shared__ float sx[4][64];
  int tid = blockIdx.x * 256 + threadIdx.x;   // exactly N*64 threads
  int n = tid >> 6, k = tid & 63;
  int w = threadIdx.x >> 6;
  float acc = bemb[k];
  const float* arow = na + n * 10;
#pragma unroll
  for (int j = 0; j < 10; ++j)
    acc = fmaf(arow[j] * 0.25f, Wemb[j * 64 + k], acc);
  acc = fmaf(t[batch[n]], Wemb[10 * 64 + k], acc);
  h[tid] = acc;
  nf0[tid] = acc;
  if (k < 3) pos_cur[n * 3 + k] = pos_in[n * 3 + k];
  sx[w][k] = acc;
  __syncthreads();
  float up = 0.f;
  for (int hh = 0; hh < 64; ++hh)
    up = fmaf(sx[w][hh], Wup0[hh * 64 + k], up);
  nfup0[tid] = up;
}

// single-block exclusive scan: thread owns 10 elems, one 1024-wide scan of partials
__global__ __launch_bounds__(1024) void k_scan(const int* __restrict__ counts,
                                               int* __restrict__ offs) {
  __shared__ int part[1024];
  int tid = threadIdx.x;
  int base = tid * 10;
  int local[10];
  int s = 0;
#pragma unroll
  for (int j = 0; j < 10; ++j) {
    int idx = base + j;
    int v = (idx < NN) ? counts[idx] : 0;
    local[j] = s;
    s += v;
  }
  part[tid] = s;
  __syncthreads();
  for (int d = 1; d < 1024; d <<= 1) {
    int v = (tid >= d) ? part[tid - d] : 0;
    __syncthreads();
    part[tid] += v;
    __syncthreads();
  }
  int excl = (tid == 0) ? 0 : part[tid - 1];
#pragma unroll
  for (int j = 0; j < 10; ++j) {
    int idx = base + j;
    if (idx < NN) offs[idx] = excl + local[j];
  }
  if (tid == 1023) offs[NN] = excl + s;
}

// eslot[e] = CSR slot of edge e (grouped by rcv)
__global__ __launch_bounds__(256) void k_scatter(
    const int* __restrict__ ei, const int* __restrict__ offs,
    int* __restrict__ cursor, int* __restrict__ eslot) {
  int e = blockIdx.x * 256 + threadIdx.x;
  int r = ei[NEDGE + e];
  int slot = atomicAdd(&cursor[r], 1);
  eslot[e] = offs[r] + slot;
}

// ---------------- per-layer ----------------
// k_edge v4: 4 edges/thread x 16 outputs/thread (output quarter = wave index).
// Block 256 thr = 4 waves; lane owns edges [blk*256 + lane*4 .. +4); all 4
// waves process the same 256 edges, each computing a different 16-col output
// quarter. acc[4][4] float4 = 64 VGPR (no spill, cf. v3's 128 -> scratch).
// Grid 625 -> 2500 waves (2.4/SIMD) and 256 broadcast b128/wave -> ~12.5us
// LDS-issue floor, ~11us VALU, overlapping.
__global__ __launch_bounds__(256) void k_edge(
    const int* __restrict__ ei, const float* __restrict__ shifts,
    const float* __restrict__ pos, const float* __restrict__ nfup0,
    const float* __restrict__ Wr1, const float* __restrict__ br1,
    const float* __restrict__ Wr2, const int* __restrict__ eslot,
    float* __restrict__ w_s, float4* __restrict__ y_s) {
  __shared__ float4 sW[1024];          // Wr2 as [64 rows][16 float4]
  __shared__ float sW1[64];
  __shared__ float sB1[64];
  {
    const float4* W4 = (const float4*)Wr2;
    for (int i = threadIdx.x; i < 1024; i += 256) sW[i] = W4[i];
    if (threadIdx.x < 64) { sW1[threadIdx.x] = Wr1[threadIdx.x]; sB1[threadIdx.x] = br1[threadIdx.x]; }
  }
  __syncthreads();
  int wq   = threadIdx.x >> 6;         // wave index = output quarter (0..3)
  int lane = threadIdx.x & 63;
  int ebase = blockIdx.x * 256 + lane * 4;   // grid 625*256 = E exactly

  float len[4]; int slot[4]; int snd[4];
#pragma unroll
  for (int q = 0; q < 4; ++q) {
    int e = ebase + q;
    int s = ei[e], r = ei[NEDGE + e];
    snd[q] = s;
    float vx = pos[r * 3 + 0] - pos[s * 3 + 0] + shifts[e * 3 + 0];
    float vy = pos[r * 3 + 1] - pos[s * 3 + 1] + shifts[e * 3 + 1];
    float vz = pos[r * 3 + 2] - pos[s * 3 + 2] + shifts[e * 3 + 2];
    float l = sqrtf(vx * vx + vy * vy + vz * vz);
    len[q] = l;
    slot[q] = eslot[e];
    if (wq == 0) {
      float inv = 1.0f / (l + 1e-9f);
      const float c1 = 1.7320508f * 0.0625f;   // sqrt(3)/AVG_NEIGH
      y_s[slot[q]] = make_float4(0.0625f, c1 * vx * inv, c1 * vy * inv, c1 * vz * inv);
    }
  }

  float4 acc[4][4];
#pragma unroll
  for (int q = 0; q < 4; ++q)
#pragma unroll
    for (int j = 0; j < 4; ++j) acc[q][j] = make_float4(0.f, 0.f, 0.f, 0.f);

  const float4* sWq = sW + wq * 4;     // this wave's 4 float4 per row
  for (int hh = 0; hh < 64; ++hh) {
    float w1 = sW1[hh], b1 = sB1[hh];
    float sl[4];
#pragma unroll
    for (int q = 0; q < 4; ++q)
      sl[q] = silu_f(fmaf(len[q], w1, b1));
#pragma unroll
    for (int j = 0; j < 4; ++j) {
      float4 wv = sWq[hh * 16 + j];    // wave-uniform addr -> broadcast
#pragma unroll
      for (int q = 0; q < 4; ++q) {
        acc[q][j].x = fmaf(sl[q], wv.x, acc[q][j].x);
        acc[q][j].y = fmaf(sl[q], wv.y, acc[q][j].y);
        acc[q][j].z = fmaf(sl[q], wv.z, acc[q][j].z);
        acc[q][j].w = fmaf(sl[q], wv.w, acc[q][j].w);
      }
    }
  }

  // epilogue: w = acc * nfup0[snd, wq*16 .. wq*16+16), write to CSR slot
#pragma unroll
  for (int q = 0; q < 4; ++q) {
    const float4* nrow = (const float4*)(nfup0 + (size_t)snd[q] * 64) + wq * 4;
    float4* wrow = (float4*)(w_s + (size_t)slot[q] * 64) + wq * 4;
#pragma unroll
    for (int j = 0; j < 4; ++j) {
      float4 nv = nrow[j];
      float4 o;
      o.x = acc[q][j].x * nv.x; o.y = acc[q][j].y * nv.y;
      o.z = acc[q][j].z * nv.z; o.w = acc[q][j].w * nv.w;
      wrow[j] = o;
    }
  }
}

// wave-per-node CSR gather: agg[n,k,0:4] = sum_e w[e,k]*Y4[e,:]
__global__ __launch_bounds__(256) void k_gather(
    const int* __restrict__ offs, const float* __restrict__ w_s,
    const float4* __restrict__ y_s, float4* __restrict__ agg) {
  int gtid = blockIdx.x * 256 + threadIdx.x;  // N*64 threads, wave per node
  int n = gtid >> 6;
  int lane = threadIdx.x & 63;
  int beg = offs[n], end = offs[n + 1];
  float a0 = 0.f, a1 = 0.f, a2 = 0.f, a3 = 0.f;
  for (int j = beg; j < end; ++j) {
    float w = w_s[(size_t)j * 64 + lane];
    float4 y = y_s[j];
    a0 = fmaf(w, y.x, a0);
    a1 = fmaf(w, y.y, a1);
    a2 = fmaf(w, y.z, a2);
    a3 = fmaf(w, y.w, a3);
  }
  agg[(size_t)n * 64 + lane] = make_float4(a0, a1, a2, a3);
}

// a = agg@Wmix ; f=1+s+s^2 ; nf=(a*f)@Wprod ; nf0=nf[...,0], v3=nf[...,1:4]
// optionally: nfup0 = nf0_row @ Wup_next (fused next-layer up).  512 thr, 56KB LDS.
__global__ __launch_bounds__(512) void k_mix_prod(
    const float4* __restrict__ agg, const float* __restrict__ Wmix,
    const float* __restrict__ Wprod, float* __restrict__ nf0,
    float* __restrict__ v3, const float* __restrict__ Wup_next,
    float* __restrict__ nfup0) {
  __shared__ float sMix[4096];
  __shared__ float sProd[4096];
  __shared__ float sUp[4096];
  __shared__ float4 xb[8][64];
  for (int i = threadIdx.x; i < 4096; i += 512) { sMix[i] = Wmix[i]; sProd[i] = Wprod[i]; }
  if (Wup_next)
    for (int i = threadIdx.x; i < 4096; i += 512) sUp[i] = Wup_next[i];
  int w = threadIdx.x >> 6, lane = threadIdx.x & 63;
  __syncthreads();
  for (int it = 0; it < 5; ++it) {
    int n = it * 2000 + blockIdx.x * 8 + w;   // grid 250: covers 0..9999 exactly
    xb[w][lane] = agg[(size_t)n * 64 + lane];
    __syncthreads();
    float4 a = make_float4(0.f, 0.f, 0.f, 0.f);
    for (int hh = 0; hh < 64; ++hh) {
      float4 x = xb[w][hh];
      float m = sMix[hh * 64 + lane];
      a.x = fmaf(x.x, m, a.x); a.y = fmaf(x.y, m, a.y);
      a.z = fmaf(x.z, m, a.z); a.w = fmaf(x.w, m, a.w);
    }
    float sv = a.x;
    float f = 1.0f + sv + sv * sv;
    a.x *= f; a.y *= f; a.z *= f; a.w *= f;
    __syncthreads();
    xb[w][lane] = a;
    __syncthreads();
    float4 nf = make_float4(0.f, 0.f, 0.f, 0.f);
    for (int hh = 0; hh < 64; ++hh) {
      float4 x = xb[w][hh];
      float m = sProd[hh * 64 + lane];
      nf.x = fmaf(x.x, m, nf.x); nf.y = fmaf(x.y, m, nf.y);
      nf.z = fmaf(x.z, m, nf.z); nf.w = fmaf(x.w, m, nf.w);
    }
    nf0[(size_t)n * 64 + lane] = nf.x;
    v3[(size_t)n * 192 + lane * 3 + 0] = nf.y;
    v3[(size_t)n * 192 + lane * 3 + 1] = nf.z;
    v3[(size_t)n * 192 + lane * 3 + 2] = nf.w;
    if (Wup_next) {
      __syncthreads();
      xb[w][lane].x = nf.x;
      __syncthreads();
      float up = 0.f;
      for (int hh = 0; hh < 64; ++hh)
        up = fmaf(xb[w][hh].x, sUp[hh * 64 + lane], up);
      nfup0[(size_t)n * 64 + lane] = up;
    }
    __syncthreads();
  }
}

// fused readout + MLP: q=silu(sc@Wro1+b) ; gate=silu(sc@Wg) ; pos += sum v3*gate*wv ;
// scalars=q@Wro2 ; h += silu([h,scalars]@Wmlp1+b)@Wmlp2 + b2.   512 thr, ~107KB LDS.
__global__ __launch_bounds__(512) void k_readout_mlp(
    const float* __restrict__ nf0, const float* __restrict__ v3,
    const float* __restrict__ Wro1, const float* __restrict__ bro1,
    const float* __restrict__ Wg, const float* __restrict__ wvv,
    const float* __restrict__ Wro2,
    const float* __restrict__ Wmlp1, const float* __restrict__ bmlp1,
    const float* __restrict__ Wmlp2, const float* __restrict__ bmlp2,
    float* __restrict__ pos, float* __restrict__ h) {
  __shared__ float sR[4096];
  __shared__ float sG[4096];
  __shared__ float sRo2[4096];
  __shared__ float sM1[8192];
  __shared__ float sM2[4096];
  __shared__ float sx[8][64], sq[8][64], ssc[8][64], sh[8][64], su[8][64];
  __shared__ float swv[64];
  for (int i = threadIdx.x; i < 4096; i += 512) {
    sR[i] = Wro1[i]; sG[i] = Wg[i]; sRo2[i] = Wro2[i]; sM2[i] = Wmlp2[i];
  }
  for (int i = threadIdx.x; i < 8192; i += 512) sM1[i] = Wmlp1[i];
  if (threadIdx.x < 64) swv[threadIdx.x] = wvv[threadIdx.x];
  int w = threadIdx.x >> 6, lane = threadIdx.x & 63;
  __syncthreads();
  for (int it = 0; it < 5; ++it) {
    int n = it * 2000 + blockIdx.x * 8 + w;
    sx[w][lane] = nf0[(size_t)n * 64 + lane];
    sh[w][lane] = h[(size_t)n * 64 + lane];
    __syncthreads();
    float q = bro1[lane];
    float g = 0.f;
    for (int hh = 0; hh < 64; ++hh) {
      float x = sx[w][hh];
      q = fmaf(x, sR[hh * 64 + lane], q);
      g = fmaf(x, sG[hh * 64 + lane], g);
    }
    q = silu_f(q);
    g = silu_f(g);
    float gw = g * swv[lane];
    float p0 = v3[(size_t)n * 192 + lane * 3 + 0] * gw;
    float p1 = v3[(size_t)n * 192 + lane * 3 + 1] * gw;
    float p2 = v3[(size_t)n * 192 + lane * 3 + 2] * gw;
#pragma unroll
    for (int m = 32; m > 0; m >>= 1) {
      p0 += __shfl_xor(p0, m);
      p1 += __shfl_xor(p1, m);
      p2 += __shfl_xor(p2, m);
    }
    if (lane == 0) {
      pos[n * 3 + 0] += p0;
      pos[n * 3 + 1] += p1;
      pos[n * 3 + 2] += p2;
    }
    sq[w][lane] = q;
    __syncthreads();
    float sc = 0.f;
    for (int m = 0; m < 64; ++m) sc = fmaf(sq[w][m], sRo2[m * 64 + lane], sc);
    ssc[w][lane] = sc;
    __syncthreads();
    float u = bmlp1[lane];
    for (int j = 0; j < 64; ++j) u = fmaf(sh[w][j], sM1[j * 64 + lane], u);
    for (int j = 0; j < 64; ++j) u = fmaf(ssc[w][j], sM1[(64 + j) * 64 + lane], u);
    u = silu_f(u);
    su[w][lane] = u;
    __syncthreads();
    float ho = sh[w][lane] + bmlp2[lane];
    for (int m = 0; m < 64; ++m) ho = fmaf(su[w][m], sM2[m * 64 + lane], ho);
    h[(size_t)n * 64 + lane] = ho;
    __syncthreads();
  }
}

// ---------------- outputs ----------------
__global__ __launch_bounds__(256) void k_pred(
    const float* __restrict__ h, const float* __restrict__ Wout,
    const float* __restrict__ bout, float* __restrict__ out) {
  __shared__ float sW[704];
  for (int i = threadIdx.x; i < 704; i += 256) sW[i] = Wout[i];
  __syncthreads();
  int n = blockIdx.x * 256 + threadIdx.x;
  if (n >= NN) return;
  float acc[10];
#pragma unroll
  for (int j = 0; j < 10; ++j) acc[j] = bout[j];
  const float* row = h + (size_t)n * 64;
  for (int hh = 0; hh < 64; ++hh) {
    float hv = row[hh];
#pragma unroll
    for (int j = 0; j < 10; ++j) acc[j] = fmaf(hv, sW[hh * 11 + j], acc[j]);
  }
  float* orow = out + (size_t)n * 10;
#pragma unroll
  for (int j = 0; j < 10; ++j) orow[j] = acc[j];
}

// batch is SORTED: wave-level segmented reduce, atomics only at run heads
__global__ __launch_bounds__(256) void k_batch(
    const int* __restrict__ batch, const float* __restrict__ pos,
    float* __restrict__ bacc) {
  int n = blockIdx.x * 256 + threadIdx.x;
  int lane = threadIdx.x & 63;
  bool valid = n < NN;
  int b = valid ? batch[n] : -1;
  float p0 = valid ? pos[n * 3 + 0] : 0.f;
  float p1 = valid ? pos[n * 3 + 1] : 0.f;
  float p2 = valid ? pos[n * 3 + 2] : 0.f;
  float c  = valid ? 1.f : 0.f;
#pragma unroll
  for (int d = 1; d < 64; d <<= 1) {
    float q0 = __shfl_down(p0, d);
    float q1 = __shfl_down(p1, d);
    float q2 = __shfl_down(p2, d);
    float qc = __shfl_down(c, d);
    int bd   = __shfl_down(b, d);
    if (lane + d < 64 && bd == b) { p0 += q0; p1 += q1; p2 += q2; c += qc; }
  }
  int bprev = __shfl_up(b, 1);
  bool head = valid && (lane == 0 || bprev != b);
  if (head) {
    atomicAdd(&bacc[b * 4 + 0], p0);
    atomicAdd(&bacc[b * 4 + 1], p1);
    atomicAdd(&bacc[b * 4 + 2], p2);
    atomicAdd(&bacc[b * 4 + 3], c);
  }
}

__global__ __launch_bounds__(256) void k_predpos(
    const int* __restrict__ batch, const float* __restrict__ pos,
    const float* __restrict__ pos0, const float* __restrict__ bacc,
    float* __restrict__ out) {
  int n = blockIdx.x * 256 + threadIdx.x;
  if (n >= NN) return;
  int b = batch[n];
  float cnt = fmaxf(bacc[b * 4 + 3], 1.0f);
#pragma unroll
  for (int c = 0; c < 3; ++c)
    out[NN * 10 + n * 3 + c] = pos[n * 3 + c] - bacc[b * 4 + c] / cnt - pos0[n * 3 + c];
}

extern "C" void kernel_launch(void* const* d_in, const int* in_sizes, int n_in,
                              void* d_out, int out_size, void* d_ws, size_t ws_size,
                              hipStream_t stream) {
  const float* positions = (const float*)d_in[0];
  const float* node_attrs = (const float*)d_in[1];
  const float* t_in = (const float*)d_in[2];
  const float* shifts = (const float*)d_in[3];
  const int* batch = (const int*)d_in[4];
  const int* edge_index = (const int*)d_in[5];
  const float* W_emb = (const float*)d_in[6];
  const float* b_emb = (const float*)d_in[7];
  const float* W_out = (const float*)d_in[8];
  const float* b_out = (const float*)d_in[9];
  const float* Wr1 = (const float*)d_in[10];
  const float* br1 = (const float*)d_in[11];
  const float* Wr2 = (const float*)d_in[12];
  const float* W_up = (const float*)d_in[13];
  const float* W_mix = (const float*)d_in[14];
  const float* W_prod = (const float*)d_in[15];
  const float* Wro1 = (const float*)d_in[16];
  const float* bro1 = (const float*)d_in[17];
  const float* Wro2 = (const float*)d_in[18];
  const float* Wg = (const float*)d_in[19];
  const float* wv = (const float*)d_in[20];
  const float* Wmlp1 = (const float*)d_in[21];
  const float* bmlp1 = (const float*)d_in[22];
  const float* Wmlp2 = (const float*)d_in[23];
  const float* bmlp2 = (const float*)d_in[24];

  float* ws = (float*)d_ws;
  float* pos_cur = ws + OFF_POS;
  float* hbuf    = ws + OFF_H;
  float* nf0     = ws + OFF_NF0;
  float* nfup0   = ws + OFF_NUP;
  float* v3      = ws + OFF_V3;
  float4* agg    = (float4*)(ws + OFF_AGG);
  float* w_s     = ws + OFF_WW;
  float4* y_s    = (float4*)(ws + OFF_WY);
  int* eslot     = (int*)(ws + OFF_ESLOT);
  int* csroff    = (int*)(ws + OFF_CSR);
  int* counts    = (int*)(ws + OFF_CNT);
  int* cursor    = (int*)(ws + OFF_CUR);
  float* bacc    = ws + OFF_BACC;

  hipMemsetAsync(counts, 0, (WS_END - OFF_CNT) * sizeof(float), stream);

  k_embed_count_up<<<3125, 256, 0, stream>>>(positions, node_attrs, t_in, batch,
                                             W_emb, b_emb, W_up,
                                             hbuf, nf0, pos_cur, nfup0,
                                             edge_index, counts);
  k_scan<<<1, 1024, 0, stream>>>(counts, csroff);
  k_scatter<<<625, 256, 0, stream>>>(edge_index, csroff, cursor, eslot);

  for (int i = 0; i < 2; ++i) {
    k_edge<<<625, 256, 0, stream>>>(edge_index, shifts, pos_cur, nfup0,
                                    Wr1 + i * 64, br1 + i * 64, Wr2 + i * 4096,
                                    eslot, w_s, y_s);
    k_gather<<<2500, 256, 0, stream>>>(csroff, w_s, y_s, agg);
    k_mix_prod<<<250, 512, 0, stream>>>(agg, W_mix + i * 4096, W_prod + i * 4096,
                                        nf0, v3,
                                        (i == 0) ? (W_up + 4096) : nullptr, nfup0);
    k_readout_mlp<<<250, 512, 0, stream>>>(nf0, v3, Wro1 + i * 4096, bro1 + i * 64,
                                           Wg + i * 4096, wv + i * 64,
                                           Wro2 + i * 4096,
                                           Wmlp1 + i * 8192, bmlp1 + i * 64,
                                           Wmlp2 + i * 4096, bmlp2 + i * 64,
                                           pos_cur, hbuf);
  }

  k_pred<<<40, 256, 0, stream>>>(hbuf, W_out, b_out, (float*)d_out);
  k_batch<<<40, 256, 0, stream>>>(batch, pos_cur, bacc);
  k_predpos<<<40, 256, 0, stream>>>(batch, pos_cur, positions, bacc, (float*)d_out);
}

// Round 11
// 389.042 us; speedup vs baseline: 1.0787x; 1.0342x over previous
//
#include <hip/hip_runtime.h>

#define NN 10000
#define NEDGE 160000
#define NBATCH 64

// ---------------- workspace layout (units: floats) ----------------
static constexpr size_t OFF_POS   = 0;                     // N*3
static constexpr size_t OFF_H     = 30016;                 // N*64
static constexpr size_t OFF_NF0   = OFF_H   + 640000;      // N*64
static constexpr size_t OFF_NUP   = OFF_NF0 + 640000;      // N*64
static constexpr size_t OFF_V3    = OFF_NUP + 640000;      // N*192
static constexpr size_t OFF_Q1    = OFF_V3  + 1920000;     // (unused)
static constexpr size_t OFF_AGG   = OFF_Q1  + 640000;      // N*256 (float4[N*64])
static constexpr size_t OFF_WW    = OFF_AGG + 2560000;     // E*64
static constexpr size_t OFF_WY    = OFF_WW  + 10240000;    // E*4 (float4[E])
static constexpr size_t OFF_ESLOT = OFF_WY  + 640000;      // E ints
static constexpr size_t OFF_CSR   = OFF_ESLOT + 160000;    // N+1 ints (pad 10016)
static constexpr size_t OFF_CNT   = OFF_CSR + 10016;       // N ints
static constexpr size_t OFF_CUR   = OFF_CNT + 10016;       // N ints
static constexpr size_t OFF_BACC  = OFF_CUR + 10016;       // B*4 floats
static constexpr size_t WS_END    = OFF_BACC + 256;

__device__ __forceinline__ float silu_f(float x) {
  return x / (1.0f + __expf(-x));
}

// ---------------- setup ----------------
__global__ __launch_bounds__(256) void k_embed_count_up(
    const float* __restrict__ pos_in, const float* __restrict__ na,
    const float* __restrict__ t, const int* __restrict__ batch,
    const float* __restrict__ Wemb, const float* __restrict__ bemb,
    const float* __restrict__ Wup0,
    float* __restrict__ h, float* __restrict__ nf0, float* __restrict__ pos_cur,
    float* __restrict__ nfup0,
    const int* __restrict__ ei, int* __restrict__ counts) {
  if (blockIdx.x >= 2500) {
    int e = (blockIdx.x - 2500) * 256 + threadIdx.x;   // exactly E threads
    atomicAdd(&counts[ei[NEDGE + e]], 1);
    return;
  }
  __shared__ float sx[4][64];
  int tid = blockIdx.x * 256 + threadIdx.x;   // exactly N*64 threads
  int n = tid >> 6, k = tid & 63;
  int w = threadIdx.x >> 6;
  float acc = bemb[k];
  const float* arow = na + n * 10;
#pragma unroll
  for (int j = 0; j < 10; ++j)
    acc = fmaf(arow[j] * 0.25f, Wemb[j * 64 + k], acc);
  acc = fmaf(t[batch[n]], Wemb[10 * 64 + k], acc);
  h[tid] = acc;
  nf0[tid] = acc;
  if (k < 3) pos_cur[n * 3 + k] = pos_in[n * 3 + k];
  sx[w][k] = acc;
  __syncthreads();
  float up = 0.f;
  for (int hh = 0; hh < 64; ++hh)
    up = fmaf(sx[w][hh], Wup0[hh * 64 + k], up);
  nfup0[tid] = up;
}

__global__ __launch_bounds__(1024) void k_scan(const int* __restrict__ counts,
                                               int* __restrict__ offs) {
  __shared__ int part[1024];
  int tid = threadIdx.x;
  int base = tid * 10;
  int local[10];
  int s = 0;
#pragma unroll
  for (int j = 0; j < 10; ++j) {
    int idx = base + j;
    int v = (idx < NN) ? counts[idx] : 0;
    local[j] = s;
    s += v;
  }
  part[tid] = s;
  __syncthreads();
  for (int d = 1; d < 1024; d <<= 1) {
    int v = (tid >= d) ? part[tid - d] : 0;
    __syncthreads();
    part[tid] += v;
    __syncthreads();
  }
  int excl = (tid == 0) ? 0 : part[tid - 1];
#pragma unroll
  for (int j = 0; j < 10; ++j) {
    int idx = base + j;
    if (idx < NN) offs[idx] = excl + local[j];
  }
  if (tid == 1023) offs[NN] = excl + s;
}

__global__ __launch_bounds__(256) void k_scatter(
    const int* __restrict__ ei, const int* __restrict__ offs,
    int* __restrict__ cursor, int* __restrict__ eslot) {
  int e = blockIdx.x * 256 + threadIdx.x;
  int r = ei[NEDGE + e];
  int slot = atomicAdd(&cursor[r], 1);
  eslot[e] = offs[r] + slot;
}

// ---------------- per-layer ----------------
// k_edge v5 = v4 structure + __launch_bounds__(256,2): VGPR cap 256 so the
// 64-VGPR acc[4][4] does NOT spill (v4 got capped at 68 -> scratch).
__global__ __launch_bounds__(256, 2) void k_edge(
    const int* __restrict__ ei, const float* __restrict__ shifts,
    const float* __restrict__ pos, const float* __restrict__ nfup0,
    const float* __restrict__ Wr1, const float* __restrict__ br1,
    const float* __restrict__ Wr2, const int* __restrict__ eslot,
    float* __restrict__ w_s, float4* __restrict__ y_s) {
  __shared__ float4 sW[1024];          // Wr2 as [64 rows][16 float4]
  __shared__ float sW1[64];
  __shared__ float sB1[64];
  {
    const float4* W4 = (const float4*)Wr2;
    for (int i = threadIdx.x; i < 1024; i += 256) sW[i] = W4[i];
    if (threadIdx.x < 64) { sW1[threadIdx.x] = Wr1[threadIdx.x]; sB1[threadIdx.x] = br1[threadIdx.x]; }
  }
  __syncthreads();
  int wq   = threadIdx.x >> 6;         // wave index = output quarter (0..3)
  int lane = threadIdx.x & 63;
  int ebase = blockIdx.x * 256 + lane * 4;   // grid 625*256 = E exactly

  float len[4]; int slot[4]; int snd[4];
#pragma unroll
  for (int q = 0; q < 4; ++q) {
    int e = ebase + q;
    int s = ei[e], r = ei[NEDGE + e];
    snd[q] = s;
    float vx = pos[r * 3 + 0] - pos[s * 3 + 0] + shifts[e * 3 + 0];
    float vy = pos[r * 3 + 1] - pos[s * 3 + 1] + shifts[e * 3 + 1];
    float vz = pos[r * 3 + 2] - pos[s * 3 + 2] + shifts[e * 3 + 2];
    float l = sqrtf(vx * vx + vy * vy + vz * vz);
    len[q] = l;
    slot[q] = eslot[e];
    if (wq == 0) {
      float inv = 1.0f / (l + 1e-9f);
      const float c1 = 1.7320508f * 0.0625f;   // sqrt(3)/AVG_NEIGH
      y_s[slot[q]] = make_float4(0.0625f, c1 * vx * inv, c1 * vy * inv, c1 * vz * inv);
    }
  }

  float4 acc[4][4];
#pragma unroll
  for (int q = 0; q < 4; ++q)
#pragma unroll
    for (int j = 0; j < 4; ++j) acc[q][j] = make_float4(0.f, 0.f, 0.f, 0.f);

  const float4* sWq = sW + wq * 4;     // this wave's 4 float4 per row
  for (int hh = 0; hh < 64; ++hh) {
    float w1 = sW1[hh], b1 = sB1[hh];
    float sl[4];
#pragma unroll
    for (int q = 0; q < 4; ++q)
      sl[q] = silu_f(fmaf(len[q], w1, b1));
#pragma unroll
    for (int j = 0; j < 4; ++j) {
      float4 wv = sWq[hh * 16 + j];    // wave-uniform addr -> broadcast
#pragma unroll
      for (int q = 0; q < 4; ++q) {
        acc[q][j].x = fmaf(sl[q], wv.x, acc[q][j].x);
        acc[q][j].y = fmaf(sl[q], wv.y, acc[q][j].y);
        acc[q][j].z = fmaf(sl[q], wv.z, acc[q][j].z);
        acc[q][j].w = fmaf(sl[q], wv.w, acc[q][j].w);
      }
    }
  }

#pragma unroll
  for (int q = 0; q < 4; ++q) {
    const float4* nrow = (const float4*)(nfup0 + (size_t)snd[q] * 64) + wq * 4;
    float4* wrow = (float4*)(w_s + (size_t)slot[q] * 64) + wq * 4;
#pragma unroll
    for (int j = 0; j < 4; ++j) {
      float4 nv = nrow[j];
      float4 o;
      o.x = acc[q][j].x * nv.x; o.y = acc[q][j].y * nv.y;
      o.z = acc[q][j].z * nv.z; o.w = acc[q][j].w * nv.w;
      wrow[j] = o;
    }
  }
}

// wave-per-node CSR gather (unchanged)
__global__ __launch_bounds__(256) void k_gather(
    const int* __restrict__ offs, const float* __restrict__ w_s,
    const float4* __restrict__ y_s, float4* __restrict__ agg) {
  int gtid = blockIdx.x * 256 + threadIdx.x;
  int n = gtid >> 6;
  int lane = threadIdx.x & 63;
  int beg = offs[n], end = offs[n + 1];
  float a0 = 0.f, a1 = 0.f, a2 = 0.f, a3 = 0.f;
  for (int j = beg; j < end; ++j) {
    float w = w_s[(size_t)j * 64 + lane];
    float4 y = y_s[j];
    a0 = fmaf(w, y.x, a0);
    a1 = fmaf(w, y.y, a1);
    a2 = fmaf(w, y.z, a2);
    a3 = fmaf(w, y.w, a3);
  }
  agg[(size_t)n * 64 + lane] = make_float4(a0, a1, a2, a3);
}

// k_mix_prod v2: 4 nodes/wave, 4 output cols/lane; weights via ds_read_b128.
// Per hh: 1 b128 weight read (16 distinct 16B chunks, conflict-free) + 1
// node-broadcast read serve 16 FMA. Wave-private LDS rows -> no barriers in
// compute. Block = 16 nodes, grid 625. LDS ~113KB -> 1 block/CU.
__global__ __launch_bounds__(256) void k_mix_prod(
    const float4* __restrict__ agg, const float* __restrict__ Wmix,
    const float* __restrict__ Wprod, float* __restrict__ nf0,
    float* __restrict__ v3, const float* __restrict__ Wup_next,
    float* __restrict__ nfup0) {
  __shared__ float sMix[4096];
  __shared__ float sProd[4096];
  __shared__ float sUp[4096];
  __shared__ float4 xa[16][65];        // pitch 65 -> quads hit distinct banks
  for (int i = threadIdx.x; i < 4096; i += 256) { sMix[i] = Wmix[i]; sProd[i] = Wprod[i]; }
  if (Wup_next)
    for (int i = threadIdx.x; i < 4096; i += 256) sUp[i] = Wup_next[i];
  int nb = blockIdx.x * 16;
  for (int i = threadIdx.x; i < 1024; i += 256)
    xa[i >> 6][i & 63] = agg[(size_t)nb * 64 + i];
  __syncthreads();

  int lane = threadIdx.x & 63, w = threadIdx.x >> 6;
  int q = lane >> 4, c16 = lane & 15;
  int nloc = w * 4 + q;                // wave-private rows [4w,4w+4)
  int n = nb + nloc;
  int col0 = c16 * 4;

  // mix: a[n,col0+j,c] = sum_h agg[n,h,c]*Wmix[h,col0+j]
  float4 a0 = {0,0,0,0}, a1 = {0,0,0,0}, a2 = {0,0,0,0}, a3 = {0,0,0,0};
  for (int hh = 0; hh < 64; ++hh) {
    float4 xv = xa[nloc][hh];
    float4 wm = *(const float4*)&sMix[hh * 64 + col0];
    a0.x = fmaf(xv.x, wm.x, a0.x); a0.y = fmaf(xv.y, wm.x, a0.y);
    a0.z = fmaf(xv.z, wm.x, a0.z); a0.w = fmaf(xv.w, wm.x, a0.w);
    a1.x = fmaf(xv.x, wm.y, a1.x); a1.y = fmaf(xv.y, wm.y, a1.y);
    a1.z = fmaf(xv.z, wm.y, a1.z); a1.w = fmaf(xv.w, wm.y, a1.w);
    a2.x = fmaf(xv.x, wm.z, a2.x); a2.y = fmaf(xv.y, wm.z, a2.y);
    a2.z = fmaf(xv.z, wm.z, a2.z); a2.w = fmaf(xv.w, wm.z, a2.w);
    a3.x = fmaf(xv.x, wm.w, a3.x); a3.y = fmaf(xv.y, wm.w, a3.y);
    a3.z = fmaf(xv.z, wm.w, a3.z); a3.w = fmaf(xv.w, wm.w, a3.w);
  }
  // f = 1+s+s^2 per (n,k): s = channel-0 of own column
  {
    float s0 = a0.x, f0 = 1.0f + s0 + s0 * s0;
    float s1 = a1.x, f1 = 1.0f + s1 + s1 * s1;
    float s2 = a2.x, f2 = 1.0f + s2 + s2 * s2;
    float s3 = a3.x, f3 = 1.0f + s3 + s3 * s3;
    a0.x *= f0; a0.y *= f0; a0.z *= f0; a0.w *= f0;
    a1.x *= f1; a1.y *= f1; a1.z *= f1; a1.w *= f1;
    a2.x *= f2; a2.y *= f2; a2.z *= f2; a2.w *= f2;
    a3.x *= f3; a3.y *= f3; a3.z *= f3; a3.w *= f3;
  }
  // exchange a within wave-private rows
  xa[nloc][col0 + 0] = a0; xa[nloc][col0 + 1] = a1;
  xa[nloc][col0 + 2] = a2; xa[nloc][col0 + 3] = a3;

  // prod
  float4 p0 = {0,0,0,0}, p1 = {0,0,0,0}, p2 = {0,0,0,0}, p3 = {0,0,0,0};
  for (int hh = 0; hh < 64; ++hh) {
    float4 xv = xa[nloc][hh];
    float4 wm = *(const float4*)&sProd[hh * 64 + col0];
    p0.x = fmaf(xv.x, wm.x, p0.x); p0.y = fmaf(xv.y, wm.x, p0.y);
    p0.z = fmaf(xv.z, wm.x, p0.z); p0.w = fmaf(xv.w, wm.x, p0.w);
    p1.x = fmaf(xv.x, wm.y, p1.x); p1.y = fmaf(xv.y, wm.y, p1.y);
    p1.z = fmaf(xv.z, wm.y, p1.z); p1.w = fmaf(xv.w, wm.y, p1.w);
    p2.x = fmaf(xv.x, wm.z, p2.x); p2.y = fmaf(xv.y, wm.z, p2.y);
    p2.z = fmaf(xv.z, wm.z, p2.z); p2.w = fmaf(xv.w, wm.z, p2.w);
    p3.x = fmaf(xv.x, wm.w, p3.x); p3.y = fmaf(xv.y, wm.w, p3.y);
    p3.z = fmaf(xv.z, wm.w, p3.z); p3.w = fmaf(xv.w, wm.w, p3.w);
  }
  // outputs: nf0 = p.x (float4 of 4 cols), v3 = p.yzw (12 consecutive floats)
  *(float4*)&nf0[(size_t)n * 64 + col0] = make_float4(p0.x, p1.x, p2.x, p3.x);
  {
    float4* v3p = (float4*)&v3[(size_t)n * 192 + col0 * 3];
    v3p[0] = make_float4(p0.y, p0.z, p0.w, p1.y);
    v3p[1] = make_float4(p1.z, p1.w, p2.y, p2.z);
    v3p[2] = make_float4(p2.w, p3.y, p3.z, p3.w);
  }
  if (Wup_next) {
    xa[nloc][col0 + 0] = p0; xa[nloc][col0 + 1] = p1;
    xa[nloc][col0 + 2] = p2; xa[nloc][col0 + 3] = p3;
    float u0 = 0.f, u1 = 0.f, u2 = 0.f, u3 = 0.f;
    for (int hh = 0; hh < 64; ++hh) {
      float xs = xa[nloc][hh].x;
      float4 wu = *(const float4*)&sUp[hh * 64 + col0];
      u0 = fmaf(xs, wu.x, u0); u1 = fmaf(xs, wu.y, u1);
      u2 = fmaf(xs, wu.z, u2); u3 = fmaf(xs, wu.w, u3);
    }
    *(float4*)&nfup0[(size_t)n * 64 + col0] = make_float4(u0, u1, u2, u3);
  }
}

// k_readout_mlp v2: same 4-nodes/wave x 4-cols/lane pattern.
// LDS ~109KB -> 1 block/CU. No barriers after the initial load.
__global__ __launch_bounds__(256) void k_readout_mlp(
    const float* __restrict__ nf0, const float* __restrict__ v3,
    const float* __restrict__ Wro1, const float* __restrict__ bro1,
    const float* __restrict__ Wg, const float* __restrict__ wvv,
    const float* __restrict__ Wro2,
    const float* __restrict__ Wmlp1, const float* __restrict__ bmlp1,
    const float* __restrict__ Wmlp2, const float* __restrict__ bmlp2,
    float* __restrict__ pos, float* __restrict__ h) {
  __shared__ float sR[4096];
  __shared__ float sG[4096];
  __shared__ float sRo2[4096];
  __shared__ float sM1[8192];
  __shared__ float sM2[4096];
  __shared__ float xs[16][68];         // pitch 68: quads distinct banks, 16B-aligned rows
  __shared__ float xh[16][68];
  __shared__ float xq[16][68];
  for (int i = threadIdx.x; i < 4096; i += 256) {
    sR[i] = Wro1[i]; sG[i] = Wg[i]; sRo2[i] = Wro2[i]; sM2[i] = Wmlp2[i];
  }
  for (int i = threadIdx.x; i < 8192; i += 256) sM1[i] = Wmlp1[i];
  int nb = blockIdx.x * 16;
  for (int i = threadIdx.x; i < 1024; i += 256) {
    xs[i >> 6][i & 63] = nf0[(size_t)nb * 64 + i];
    xh[i >> 6][i & 63] = h[(size_t)nb * 64 + i];
  }
  __syncthreads();

  int lane = threadIdx.x & 63, w = threadIdx.x >> 6;
  int q = lane >> 4, c16 = lane & 15;
  int nloc = w * 4 + q;
  int n = nb + nloc;
  int col0 = c16 * 4;

  // q = silu(sc@Wro1 + bro1), gate = silu(sc@Wg)
  float qa0 = 0, qa1 = 0, qa2 = 0, qa3 = 0;
  float ga0 = 0, ga1 = 0, ga2 = 0, ga3 = 0;
  for (int m = 0; m < 64; ++m) {
    float x = xs[nloc][m];
    float4 wr = *(const float4*)&sR[m * 64 + col0];
    float4 wg = *(const float4*)&sG[m * 64 + col0];
    qa0 = fmaf(x, wr.x, qa0); qa1 = fmaf(x, wr.y, qa1);
    qa2 = fmaf(x, wr.z, qa2); qa3 = fmaf(x, wr.w, qa3);
    ga0 = fmaf(x, wg.x, ga0); ga1 = fmaf(x, wg.y, ga1);
    ga2 = fmaf(x, wg.z, ga2); ga3 = fmaf(x, wg.w, ga3);
  }
  float4 b1v = *(const float4*)&bro1[col0];
  float q0 = silu_f(qa0 + b1v.x), q1 = silu_f(qa1 + b1v.y);
  float q2 = silu_f(qa2 + b1v.z), q3 = silu_f(qa3 + b1v.w);
  float g0 = silu_f(ga0), g1 = silu_f(ga1), g2 = silu_f(ga2), g3 = silu_f(ga3);

  // pos update: vout_c = sum_k v3[n,k,c]*gate_k*wv_k
  {
    float4 wv4 = *(const float4*)&wvv[col0];
    const float4* v3p = (const float4*)&v3[(size_t)n * 192 + col0 * 3];
    float4 va = v3p[0], vb = v3p[1], vc = v3p[2];
    float gw0 = g0 * wv4.x, gw1 = g1 * wv4.y, gw2 = g2 * wv4.z, gw3 = g3 * wv4.w;
    float p0 = va.x * gw0 + va.w * gw1 + vb.z * gw2 + vc.y * gw3;
    float p1 = va.y * gw0 + vb.x * gw1 + vb.w * gw2 + vc.z * gw3;
    float p2 = va.z * gw0 + vb.y * gw1 + vc.x * gw2 + vc.w * gw3;
#pragma unroll
    for (int m = 1; m < 16; m <<= 1) {
      p0 += __shfl_xor(p0, m);
      p1 += __shfl_xor(p1, m);
      p2 += __shfl_xor(p2, m);
    }
    if (c16 == 0) {
      pos[n * 3 + 0] += p0;
      pos[n * 3 + 1] += p1;
      pos[n * 3 + 2] += p2;
    }
  }

  // scalars = q @ Wro2  (exchange q via wave-private LDS row)
  *(float4*)&xq[nloc][col0] = make_float4(q0, q1, q2, q3);
  float s20 = 0, s21 = 0, s22 = 0, s23 = 0;
  for (int m = 0; m < 64; ++m) {
    float x = xq[nloc][m];
    float4 w2 = *(const float4*)&sRo2[m * 64 + col0];
    s20 = fmaf(x, w2.x, s20); s21 = fmaf(x, w2.y, s21);
    s22 = fmaf(x, w2.z, s22); s23 = fmaf(x, w2.w, s23);
  }
  *(float4*)&xs[nloc][col0] = make_float4(s20, s21, s22, s23);  // sc done, reuse

  // u = silu([h, scalars] @ Wmlp1 + bmlp1)
  float4 bm1 = *(const float4*)&bmlp1[col0];
  float u0 = bm1.x, u1 = bm1.y, u2 = bm1.z, u3 = bm1.w;
  for (int m = 0; m < 64; ++m) {
    float xm = xh[nloc][m];
    float4 m1 = *(const float4*)&sM1[m * 64 + col0];
    u0 = fmaf(xm, m1.x, u0); u1 = fmaf(xm, m1.y, u1);
    u2 = fmaf(xm, m1.z, u2); u3 = fmaf(xm, m1.w, u3);
  }
  for (int m = 0; m < 64; ++m) {
    float xm = xs[nloc][m];
    float4 m1 = *(const float4*)&sM1[(64 + m) * 64 + col0];
    u0 = fmaf(xm, m1.x, u0); u1 = fmaf(xm, m1.y, u1);
    u2 = fmaf(xm, m1.z, u2); u3 = fmaf(xm, m1.w, u3);
  }
  u0 = silu_f(u0); u1 = silu_f(u1); u2 = silu_f(u2); u3 = silu_f(u3);
  *(float4*)&xq[nloc][col0] = make_float4(u0, u1, u2, u3);      // q done, reuse

  // h += u @ Wmlp2 + bmlp2
  float4 bm2 = *(const float4*)&bmlp2[col0];
  float4 hold = *(float4*)&xh[nloc][col0];
  float h0 = hold.x + bm2.x, h1 = hold.y + bm2.y;
  float h2 = hold.z + bm2.z, h3 = hold.w + bm2.w;
  for (int m = 0; m < 64; ++m) {
    float um = xq[nloc][m];
    float4 m2 = *(const float4*)&sM2[m * 64 + col0];
    h0 = fmaf(um, m2.x, h0); h1 = fmaf(um, m2.y, h1);
    h2 = fmaf(um, m2.z, h2); h3 = fmaf(um, m2.w, h3);
  }
  *(float4*)&h[(size_t)n * 64 + col0] = make_float4(h0, h1, h2, h3);
}

// ---------------- outputs ----------------
__global__ __launch_bounds__(256) void k_pred(
    const float* __restrict__ h, const float* __restrict__ Wout,
    const float* __restrict__ bout, float* __restrict__ out) {
  __shared__ float sW[704];
  for (int i = threadIdx.x; i < 704; i += 256) sW[i] = Wout[i];
  __syncthreads();
  int n = blockIdx.x * 256 + threadIdx.x;
  if (n >= NN) return;
  float acc[10];
#pragma unroll
  for (int j = 0; j < 10; ++j) acc[j] = bout[j];
  const float* row = h + (size_t)n * 64;
  for (int hh = 0; hh < 64; ++hh) {
    float hv = row[hh];
#pragma unroll
    for (int j = 0; j < 10; ++j) acc[j] = fmaf(hv, sW[hh * 11 + j], acc[j]);
  }
  float* orow = out + (size_t)n * 10;
#pragma unroll
  for (int j = 0; j < 10; ++j) orow[j] = acc[j];
}

__global__ __launch_bounds__(256) void k_batch(
    const int* __restrict__ batch, const float* __restrict__ pos,
    float* __restrict__ bacc) {
  int n = blockIdx.x * 256 + threadIdx.x;
  int lane = threadIdx.x & 63;
  bool valid = n < NN;
  int b = valid ? batch[n] : -1;
  float p0 = valid ? pos[n * 3 + 0] : 0.f;
  float p1 = valid ? pos[n * 3 + 1] : 0.f;
  float p2 = valid ? pos[n * 3 + 2] : 0.f;
  float c  = valid ? 1.f : 0.f;
#pragma unroll
  for (int d = 1; d < 64; d <<= 1) {
    float q0 = __shfl_down(p0, d);
    float q1 = __shfl_down(p1, d);
    float q2 = __shfl_down(p2, d);
    float qc = __shfl_down(c, d);
    int bd   = __shfl_down(b, d);
    if (lane + d < 64 && bd == b) { p0 += q0; p1 += q1; p2 += q2; c += qc; }
  }
  int bprev = __shfl_up(b, 1);
  bool head = valid && (lane == 0 || bprev != b);
  if (head) {
    atomicAdd(&bacc[b * 4 + 0], p0);
    atomicAdd(&bacc[b * 4 + 1], p1);
    atomicAdd(&bacc[b * 4 + 2], p2);
    atomicAdd(&bacc[b * 4 + 3], c);
  }
}

__global__ __launch_bounds__(256) void k_predpos(
    const int* __restrict__ batch, const float* __restrict__ pos,
    const float* __restrict__ pos0, const float* __restrict__ bacc,
    float* __restrict__ out) {
  int n = blockIdx.x * 256 + threadIdx.x;
  if (n >= NN) return;
  int b = batch[n];
  float cnt = fmaxf(bacc[b * 4 + 3], 1.0f);
#pragma unroll
  for (int c = 0; c < 3; ++c)
    out[NN * 10 + n * 3 + c] = pos[n * 3 + c] - bacc[b * 4 + c] / cnt - pos0[n * 3 + c];
}

extern "C" void kernel_launch(void* const* d_in, const int* in_sizes, int n_in,
                              void* d_out, int out_size, void* d_ws, size_t ws_size,
                              hipStream_t stream) {
  const float* positions = (const float*)d_in[0];
  const float* node_attrs = (const float*)d_in[1];
  const float* t_in = (const float*)d_in[2];
  const float* shifts = (const float*)d_in[3];
  const int* batch = (const int*)d_in[4];
  const int* edge_index = (const int*)d_in[5];
  const float* W_emb = (const float*)d_in[6];
  const float* b_emb = (const float*)d_in[7];
  const float* W_out = (const float*)d_in[8];
  const float* b_out = (const float*)d_in[9];
  const float* Wr1 = (const float*)d_in[10];
  const float* br1 = (const float*)d_in[11];
  const float* Wr2 = (const float*)d_in[12];
  const float* W_up = (const float*)d_in[13];
  const float* W_mix = (const float*)d_in[14];
  const float* W_prod = (const float*)d_in[15];
  const float* Wro1 = (const float*)d_in[16];
  const float* bro1 = (const float*)d_in[17];
  const float* Wro2 = (const float*)d_in[18];
  const float* Wg = (const float*)d_in[19];
  const float* wv = (const float*)d_in[20];
  const float* Wmlp1 = (const float*)d_in[21];
  const float* bmlp1 = (const float*)d_in[22];
  const float* Wmlp2 = (const float*)d_in[23];
  const float* bmlp2 = (const float*)d_in[24];

  float* ws = (float*)d_ws;
  float* pos_cur = ws + OFF_POS;
  float* hbuf    = ws + OFF_H;
  float* nf0     = ws + OFF_NF0;
  float* nfup0   = ws + OFF_NUP;
  float* v3      = ws + OFF_V3;
  float4* agg    = (float4*)(ws + OFF_AGG);
  float* w_s     = ws + OFF_WW;
  float4* y_s    = (float4*)(ws + OFF_WY);
  int* eslot     = (int*)(ws + OFF_ESLOT);
  int* csroff    = (int*)(ws + OFF_CSR);
  int* counts    = (int*)(ws + OFF_CNT);
  int* cursor    = (int*)(ws + OFF_CUR);
  float* bacc    = ws + OFF_BACC;

  hipMemsetAsync(counts, 0, (WS_END - OFF_CNT) * sizeof(float), stream);

  k_embed_count_up<<<3125, 256, 0, stream>>>(positions, node_attrs, t_in, batch,
                                             W_emb, b_emb, W_up,
                                             hbuf, nf0, pos_cur, nfup0,
                                             edge_index, counts);
  k_scan<<<1, 1024, 0, stream>>>(counts, csroff);
  k_scatter<<<625, 256, 0, stream>>>(edge_index, csroff, cursor, eslot);

  for (int i = 0; i < 2; ++i) {
    k_edge<<<625, 256, 0, stream>>>(edge_index, shifts, pos_cur, nfup0,
                                    Wr1 + i * 64, br1 + i * 64, Wr2 + i * 4096,
                                    eslot, w_s, y_s);
    k_gather<<<2500, 256, 0, stream>>>(csroff, w_s, y_s, agg);
    k_mix_prod<<<625, 256, 0, stream>>>(agg, W_mix + i * 4096, W_prod + i * 4096,
                                        nf0, v3,
                                        (i == 0) ? (W_up + 4096) : nullptr, nfup0);
    k_readout_mlp<<<625, 256, 0, stream>>>(nf0, v3, Wro1 + i * 4096, bro1 + i * 64,
                                           Wg + i * 4096, wv + i * 64,
                                           Wro2 + i * 4096,
                                           Wmlp1 + i * 8192, bmlp1 + i * 64,
                                           Wmlp2 + i * 4096, bmlp2 + i * 64,
                                           pos_cur, hbuf);
  }

  k_pred<<<40, 256, 0, stream>>>(hbuf, W_out, b_out, (float*)d_out);
  k_batch<<<40, 256, 0, stream>>>(batch, pos_cur, bacc);
  k_predpos<<<40, 256, 0, stream>>>(batch, pos_cur, positions, bacc, (float*)d_out);
}